// Round 17
// baseline (45.150 us; speedup 1.0000x reference)
//
#include <hip/hip_runtime.h>

typedef __attribute__((ext_vector_type(16))) float f32x16;
typedef __attribute__((ext_vector_type(8))) int i32x8;

static constexpr int D = 256;
static constexpr float INV_T = 2.0f;                 // 1 / temperature(0.5)
static constexpr float KEXP2 = 2.8853900817779268f;  // 2*log2(e): exp(2x)=2^(KEXP2*x)
static constexpr int TTILE = 64;                     // 8192 / 128
static constexpr int NT = TTILE * (TTILE + 1) / 2;   // 2080 upper-triangle tiles
static constexpr int NPLANE = 2 * TTILE;             // 128 partial planes
static constexpr int LSE_BLOCKS = 256;
static constexpr unsigned int SCALE1 = 0x7F7F7F7Fu;  // e8m0 = 127 -> x1.0 per block
// zn fp8 32x32x64-fragment layout (per 128-row tile = contiguous 32 KB):
//   frag(rt,kc) at (rt*4+kc)*2048; lane l holds bytes [l*32, l*32+32):
//   element (row,k): rt=row>>5, kc=k>>6, lane=((k>>5)&1)*32+(row&31), e=k&31.
// Writer and reader share this definition; any shared A/B k-permutation
// cancels in the MFMA dot product (the R9-R16 layout-correctness argument).

__device__ inline float fexp2(float x) {
#if __has_builtin(__builtin_amdgcn_exp2f)
    return __builtin_amdgcn_exp2f(x);
#else
    return exp2f(x);
#endif
}
__device__ inline unsigned int cvt4_fp8(float a, float b, float c, float d) {
    int v = __builtin_amdgcn_cvt_pk_fp8_f32(a, b, 0, false);
    v = __builtin_amdgcn_cvt_pk_fp8_f32(c, d, v, true);
    return (unsigned int)v;
}
// byte offset of (row, k=4*l..4*l+3) in the zn layout above
__device__ inline size_t zoff(int row, int l) {
    return (size_t)(row >> 7) * 32768 + (size_t)((row >> 5) & 3) * 8192
         + (size_t)(l >> 4) * 2048 + (size_t)((l >> 3) & 1) * 1024
         + (size_t)(row & 31) * 32 + (size_t)((l & 7) * 4);
}

// Kernel 1: normalize pair rows to fp8 in the 32x32x64-fragment layout;
// diag[i] = -exp(2*selfdot_fp8); pos dot -> block partial; resets counter.
__global__ void k_norm(const float* __restrict__ zi, const float* __restrict__ zj,
                       unsigned char* __restrict__ zn, float* __restrict__ diag,
                       float* __restrict__ pos_partial, unsigned int* __restrict__ counter,
                       int B) {
    __shared__ float red[4];
    const int lane = threadIdx.x & 63;
    const int wv = threadIdx.x >> 6;
    const int i = blockIdx.x * 4 + wv;       // pair index
    if (blockIdx.x == 0 && threadIdx.x == 0) *counter = 0;
    if (i < B) {
        float4 vi = reinterpret_cast<const float4*>(zi + (size_t)i * D)[lane];
        float4 vj = reinterpret_cast<const float4*>(zj + (size_t)i * D)[lane];
        float ssi = vi.x * vi.x + vi.y * vi.y + vi.z * vi.z + vi.w * vi.w;
        float ssj = vj.x * vj.x + vj.y * vj.y + vj.z * vj.z + vj.w * vj.w;
#pragma unroll
        for (int off = 32; off >= 1; off >>= 1) {
            ssi += __shfl_xor(ssi, off, 64);
            ssj += __shfl_xor(ssj, off, 64);
        }
        float rni = rsqrtf(ssi), rnj = rsqrtf(ssj);
        unsigned int pa = cvt4_fp8(vi.x * rni, vi.y * rni, vi.z * rni, vi.w * rni);
        unsigned int pb = cvt4_fp8(vj.x * rnj, vj.y * rnj, vj.z * rnj, vj.w * rnj);
        float fa0 = __builtin_amdgcn_cvt_f32_fp8((int)pa, 0);
        float fa1 = __builtin_amdgcn_cvt_f32_fp8((int)pa, 1);
        float fa2 = __builtin_amdgcn_cvt_f32_fp8((int)pa, 2);
        float fa3 = __builtin_amdgcn_cvt_f32_fp8((int)pa, 3);
        float fb0 = __builtin_amdgcn_cvt_f32_fp8((int)pb, 0);
        float fb1 = __builtin_amdgcn_cvt_f32_fp8((int)pb, 1);
        float fb2 = __builtin_amdgcn_cvt_f32_fp8((int)pb, 2);
        float fb3 = __builtin_amdgcn_cvt_f32_fp8((int)pb, 3);
        float sdi = fa0 * fa0 + fa1 * fa1 + fa2 * fa2 + fa3 * fa3;
        float sdj = fb0 * fb0 + fb1 * fb1 + fb2 * fb2 + fb3 * fb3;
        float pd  = fa0 * fb0 + fa1 * fb1 + fa2 * fb2 + fa3 * fb3;
#pragma unroll
        for (int off = 32; off >= 1; off >>= 1) {
            sdi += __shfl_xor(sdi, off, 64);
            sdj += __shfl_xor(sdj, off, 64);
            pd  += __shfl_xor(pd, off, 64);
        }
        // per-lane 4B scatter into the fragment layout (writer==reader defn)
        *reinterpret_cast<unsigned int*>(zn + zoff(i, lane)) = pa;
        *reinterpret_cast<unsigned int*>(zn + zoff(i + B, lane)) = pb;
        if (lane == 0) {
            diag[i]     = -fexp2(KEXP2 * sdi);
            diag[i + B] = -fexp2(KEXP2 * sdj);
            red[wv] = pd;
        }
    } else if (lane == 0) {
        red[wv] = 0.f;
    }
    __syncthreads();
    if (threadIdx.x == 0)
        pos_partial[blockIdx.x] = 2.0f * INV_T * (red[0] + red[1] + red[2] + red[3]);
}

// Kernel 2: barrier-free, LDS-free upper-triangle 128x128 tiles using the
// MX-scaled 32x32x64 fp8 MFMA with unit scales: 2.14x the MFMA rate of the
// 16x16x32 path (4686 vs 2047 TF measured) and 8x fewer MFMA instructions
// (32 vs 256 per wave). 2 waves/block, wave owns 128 rows x 64 cols
// (acc = 8 x f32x16 = 128). Same plane scheme + zero-fill as R16.
__global__ __launch_bounds__(128, 2)
void k_main(const unsigned char* __restrict__ zn, float* __restrict__ P, int N) {
    const int tid = threadIdx.x;
    const int lane = tid & 63;
    const int wc = tid >> 6;                 // wave = column half (0/1)
    const int hi = lane >> 5;

    // XCD-aware bijective swizzle (NT = 2080 = 8 * 260)
    const int bid = (int)blockIdx.x;
    const int swz = (bid & 7) * (NT / 8) + (bid >> 3);
    // closed-form upper-triangle decode (verified R13)
    int ti = (int)(((float)(2 * TTILE + 1) -
                    sqrtf((float)((2 * TTILE + 1) * (2 * TTILE + 1)) - 8.0f * (float)swz)) * 0.5f);
    ti = (ti < 0) ? 0 : ((ti > TTILE - 1) ? TTILE - 1 : ti);
    while (ti > 0 && (ti * TTILE - ((ti * (ti - 1)) >> 1)) > swz) --ti;
    while (((ti + 1) * TTILE - (((ti + 1) * ti) >> 1)) <= swz) ++ti;
    const int tj = ti + (swz - (ti * TTILE - ((ti * (ti - 1)) >> 1)));

    const unsigned char* Abase = zn + (size_t)ti * 32768;
    const unsigned char* Bbase = zn + (size_t)tj * 32768;

    f32x16 acc[4][2];
#pragma unroll
    for (int rt = 0; rt < 4; ++rt)
#pragma unroll
        for (int ct = 0; ct < 2; ++ct)
#pragma unroll
            for (int g = 0; g < 16; ++g) acc[rt][ct][g] = 0.f;

#pragma unroll
    for (int kc = 0; kc < 4; ++kc) {
        i32x8 a_[4], b_[2];
#pragma unroll
        for (int rt = 0; rt < 4; ++rt)
            a_[rt] = *reinterpret_cast<const i32x8*>(Abase + (rt * 4 + kc) * 2048 + lane * 32);
#pragma unroll
        for (int ct = 0; ct < 2; ++ct)
            b_[ct] = *reinterpret_cast<const i32x8*>(
                Bbase + ((wc * 2 + ct) * 4 + kc) * 2048 + lane * 32);
        __builtin_amdgcn_s_setprio(1);
#pragma unroll
        for (int rt = 0; rt < 4; ++rt)
#pragma unroll
            for (int ct = 0; ct < 2; ++ct)
                acc[rt][ct] = __builtin_amdgcn_mfma_scale_f32_32x32x64_f8f6f4(
                    a_[rt], b_[ct], acc[rt][ct], 0, 0, 0, SCALE1, 0, SCALE1);
        __builtin_amdgcn_s_setprio(0);
    }

    // tail: e = exp(2*sim). C layout (verified m74/m101): col = lane&31,
    // row = (g&3) + 8*(g>>2) + 4*hi within each 32x32 tile.
    // Row-sums -> plane 2*tj+wc; col-sums -> plane 2*ti+wc cols
    // [tj*128+wc*64,+64), zeros to the complementary half.
    float cs0 = 0.f, cs1 = 0.f;
#pragma unroll
    for (int rt = 0; rt < 4; ++rt) {
        float rs[16];
#pragma unroll
        for (int g = 0; g < 16; ++g) {
            float e0 = fexp2(KEXP2 * acc[rt][0][g]);
            float e1 = fexp2(KEXP2 * acc[rt][1][g]);
            rs[g] = e0 + e1;
            cs0 += e0; cs1 += e1;
        }
        // reduce each row over the 32 columns (offsets 1..8 are DPP-cheap)
#pragma unroll
        for (int g = 0; g < 16; ++g) {
            rs[g] += __shfl_xor(rs[g], 1, 64);
            rs[g] += __shfl_xor(rs[g], 2, 64);
            rs[g] += __shfl_xor(rs[g], 4, 64);
            rs[g] += __shfl_xor(rs[g], 8, 64);
            rs[g] += __shfl_xor(rs[g], 16, 64);
        }
        if ((lane & 31) == 0) {
            float* Prow = P + (size_t)(2 * tj + wc) * N + ti * 128 + rt * 32 + 4 * hi;
#pragma unroll
            for (int g = 0; g < 16; ++g)
                Prow[(g & 3) + 8 * (g >> 2)] = rs[g];
        }
    }
    if (ti != tj) {
        // col-sums: lanes l and l+32 hold the same column (different rows)
        cs0 += __shfl_xor(cs0, 32, 64);
        cs1 += __shfl_xor(cs1, 32, 64);
        float* Pcol = P + (size_t)(2 * ti + wc) * N + tj * 128 + wc * 64;
        if (hi == 0) {
            Pcol[lane] = cs0;            // ct=0: cols +0..31
            Pcol[32 + lane] = cs1;       // ct=1: cols +32..63
        }
        // zero-fill the complementary 64-col half of this wave's plane
        P[(size_t)(2 * ti + wc) * N + tj * 128 + (1 - wc) * 64 + lane] = 0.f;
    }
}

// Kernel 3 (verified R15/R16): per-row plane sum (8 threads/row x 16 planes)
// + diag, log; block partial; last block combines with pos partials -> loss.
__global__ void k_lse(const float* __restrict__ P, const float* __restrict__ diag,
                      const float* __restrict__ pos_partial, int n_pos,
                      float* __restrict__ part, unsigned int* __restrict__ counter,
                      float* __restrict__ out, int N) {
    __shared__ float red[4];
    const int tid = threadIdx.x;
    const int lane = tid & 63, wv = tid >> 6;
    const int row = blockIdx.x * 32 + (tid >> 3);
    const int sub = tid & 7;
    float s = 0.f;
#pragma unroll
    for (int d = 0; d < 16; ++d)
        s += P[(size_t)(sub * 16 + d) * N + row];
    s += __shfl_xor(s, 1, 64);
    s += __shfl_xor(s, 2, 64);
    s += __shfl_xor(s, 4, 64);
    float lg = (sub == 0) ? __logf(s + diag[row]) : 0.f;
    lg += __shfl_xor(lg, 8, 64);
    lg += __shfl_xor(lg, 16, 64);
    lg += __shfl_xor(lg, 32, 64);
    if (lane == 0) red[wv] = lg;
    __syncthreads();
    bool last = false;
    if (tid == 0) {
        part[blockIdx.x] = red[0] + red[1] + red[2] + red[3];
        __threadfence();
        last = (atomicAdd(counter, 1u) == LSE_BLOCKS - 1);
    }
    __shared__ int lastflag;
    if (tid == 0) lastflag = last ? 1 : 0;
    __syncthreads();
    if (lastflag) {
        __threadfence();
        float t = 0.f;
        for (int i = tid; i < LSE_BLOCKS; i += 256) t += part[i];
        for (int i = tid; i < n_pos; i += 256) t -= pos_partial[i];
#pragma unroll
        for (int off = 32; off >= 1; off >>= 1) t += __shfl_xor(t, off, 64);
        if (lane == 0) red[wv] = t;
        __syncthreads();
        if (tid == 0)
            out[0] = (red[0] + red[1] + red[2] + red[3]) / (float)N;
    }
}

extern "C" void kernel_launch(void* const* d_in, const int* in_sizes, int n_in,
                              void* d_out, int out_size, void* d_ws, size_t ws_size,
                              hipStream_t stream) {
    const float* zi = (const float*)d_in[0];
    const float* zj = (const float*)d_in[1];
    const int B = in_sizes[0] / D;   // 4096
    const int N = 2 * B;             // 8192

    char* ws = (char*)d_ws;
    unsigned char* zn = (unsigned char*)ws;              // N*D fp8 = 2 MB
    float* diag = (float*)(ws + (size_t)N * D);          // N f32
    float* pos_partial = diag + N;                       // 1024 f32
    float* part = pos_partial + 1024;                    // 256 f32
    unsigned int* counter = (unsigned int*)(part + 256); // 1 u32
    float* P = (float*)(counter + 32);                   // 128*N f32 = 4 MB

    float* out = (float*)d_out;

    const int npb = B / 4;  // 1024 k_norm blocks == pos partials
    hipLaunchKernelGGL(k_norm, dim3(npb), dim3(256), 0, stream, zi, zj, zn, diag,
                       pos_partial, counter, B);
    hipLaunchKernelGGL(k_main, dim3(NT), dim3(128), 0, stream, zn, P, N);
    hipLaunchKernelGGL(k_lse, dim3(LSE_BLOCKS), dim3(256), 0, stream, P, diag,
                       pos_partial, npb, part, counter, out, N);
}

// Round 18
// 41.127 us; speedup vs baseline: 1.0978x; 1.0978x over previous
//
#include <hip/hip_runtime.h>

typedef __attribute__((ext_vector_type(4))) float f32x4;
typedef __attribute__((ext_vector_type(2))) long long i64x2;

static constexpr int D = 256;
static constexpr float INV_T = 2.0f;                 // 1 / temperature(0.5)
static constexpr float KEXP2 = 2.8853900817779268f;  // 2*log2(e): exp(2x)=2^(KEXP2*x)
static constexpr int TTILE = 64;                     // 8192 / 128
static constexpr int NT = TTILE * (TTILE + 1) / 2;   // 2080 upper-triangle tiles
static constexpr int NPLANE = 2 * TTILE;             // 128 partial planes
static constexpr int LSE_BLOCKS = 32;
// zn fp8 paired-kk fragment layout (verified R10-R13, absmax=0): per 128-row
// tile contiguous 32 KB; byte = ti*32768 + rb*4096 + kkp*1024 + lane*16 +
// half*8 + e, rb=(row>>4)&7, kkp=k>>6, half=(k>>5)&1,
// lane=((k>>3)&3)*16+(row&15), e=k&7.

__device__ inline float fexp2(float x) {
#if __has_builtin(__builtin_amdgcn_exp2f)
    return __builtin_amdgcn_exp2f(x);
#else
    return exp2f(x);
#endif
}
__device__ inline unsigned int cvt4_fp8(float a, float b, float c, float d) {
    int v = __builtin_amdgcn_cvt_pk_fp8_f32(a, b, 0, false);
    v = __builtin_amdgcn_cvt_pk_fp8_f32(c, d, v, true);
    return (unsigned int)v;
}

// Kernel 1 (verified R10-R13): normalize pair rows to fp8 in the fragment
// layout; diag[i] = -exp(2*selfdot_fp8); pos dot -> block partial; resets
// the k_lse completion counter.
__global__ void k_norm(const float* __restrict__ zi, const float* __restrict__ zj,
                       unsigned char* __restrict__ zn, float* __restrict__ diag,
                       float* __restrict__ pos_partial, unsigned int* __restrict__ counter,
                       int B) {
    __shared__ float red[4];
    const int lane = threadIdx.x & 63;
    const int wv = threadIdx.x >> 6;
    const int i = blockIdx.x * 4 + wv;       // pair index
    if (blockIdx.x == 0 && threadIdx.x == 0) *counter = 0;
    if (i < B) {
        float4 vi = reinterpret_cast<const float4*>(zi + (size_t)i * D)[lane];
        float4 vj = reinterpret_cast<const float4*>(zj + (size_t)i * D)[lane];
        float ssi = vi.x * vi.x + vi.y * vi.y + vi.z * vi.z + vi.w * vi.w;
        float ssj = vj.x * vj.x + vj.y * vj.y + vj.z * vj.z + vj.w * vj.w;
#pragma unroll
        for (int off = 32; off >= 1; off >>= 1) {
            ssi += __shfl_xor(ssi, off, 64);
            ssj += __shfl_xor(ssj, off, 64);
        }
        float rni = rsqrtf(ssi), rnj = rsqrtf(ssj);
        unsigned int pa = cvt4_fp8(vi.x * rni, vi.y * rni, vi.z * rni, vi.w * rni);
        unsigned int pb = cvt4_fp8(vj.x * rnj, vj.y * rnj, vj.z * rnj, vj.w * rnj);
        float fa0 = __builtin_amdgcn_cvt_f32_fp8((int)pa, 0);
        float fa1 = __builtin_amdgcn_cvt_f32_fp8((int)pa, 1);
        float fa2 = __builtin_amdgcn_cvt_f32_fp8((int)pa, 2);
        float fa3 = __builtin_amdgcn_cvt_f32_fp8((int)pa, 3);
        float fb0 = __builtin_amdgcn_cvt_f32_fp8((int)pb, 0);
        float fb1 = __builtin_amdgcn_cvt_f32_fp8((int)pb, 1);
        float fb2 = __builtin_amdgcn_cvt_f32_fp8((int)pb, 2);
        float fb3 = __builtin_amdgcn_cvt_f32_fp8((int)pb, 3);
        float sdi = fa0 * fa0 + fa1 * fa1 + fa2 * fa2 + fa3 * fa3;
        float sdj = fb0 * fb0 + fb1 * fb1 + fb2 * fb2 + fb3 * fb3;
        float pd  = fa0 * fb0 + fa1 * fb1 + fa2 * fb2 + fa3 * fb3;
#pragma unroll
        for (int off = 32; off >= 1; off >>= 1) {
            sdi += __shfl_xor(sdi, off, 64);
            sdj += __shfl_xor(sdj, off, 64);
            pd  += __shfl_xor(pd, off, 64);
        }
        unsigned int qa = __shfl_xor(pa, 1, 64);
        unsigned int qb = __shfl_xor(pb, 1, 64);
        if ((lane & 1) == 0) {
            int m = lane >> 1;   // 0..31 -> k = 8m..8m+7
            size_t base = (size_t)(m >> 3) * 1024 + (size_t)((m & 3) * 16) * 16
                        + (size_t)(((m >> 2) & 1)) * 8;
            size_t offA = (size_t)(i >> 4) * 4096 + base + (size_t)(i & 15) * 16;
            int ib = i + B;
            size_t offB = (size_t)(ib >> 4) * 4096 + base + (size_t)(ib & 15) * 16;
            *reinterpret_cast<unsigned long long*>(zn + offA) =
                ((unsigned long long)qa << 32) | pa;
            *reinterpret_cast<unsigned long long*>(zn + offB) =
                ((unsigned long long)qb << 32) | pb;
        }
        if (lane == 0) {
            diag[i]     = -fexp2(KEXP2 * sdi);
            diag[i + B] = -fexp2(KEXP2 * sdj);
            red[wv] = pd;
        }
    } else if (lane == 0) {
        red[wv] = 0.f;
    }
    __syncthreads();
    if (threadIdx.x == 0)
        pos_partial[blockIdx.x] = 2.0f * INV_T * (red[0] + red[1] + red[2] + red[3]);
}

// Kernel 2 (R11 structure verbatim -- the best-measured config, 40.5us total):
// barrier-free, LDS-free upper-triangle 128x128 tiles; 4 waves (2x2), wave
// owns 64x64; per-kkp global->VGPR fragment loads; 16x16x32 fp8 MFMA.
// Planes fully covered (row-sums: wr waves x plane 2tj+wc; col-sums: wc waves
// x plane 2ti+wr) -> no memset, no zero-fill.
__global__ __launch_bounds__(256, 2)
void k_main(const unsigned char* __restrict__ zn, float* __restrict__ P, int N) {
    const int tid = threadIdx.x;
    const int lane = tid & 63, wv = tid >> 6;
    const int l15 = lane & 15, lhi = lane >> 4;
    const int wr = wv >> 1, wc = wv & 1;         // wave grid 2 x 2, 64x64 each

    // XCD-aware bijective swizzle (NT = 2080 = 8 * 260)
    const int bid = (int)blockIdx.x;
    const int swz = (bid & 7) * (NT / 8) + (bid >> 3);
    int ti = 0, rem = swz;
    while (rem >= TTILE - ti) { rem -= TTILE - ti; ++ti; }
    const int tj = ti + rem;

    const i64x2* Ap = reinterpret_cast<const i64x2*>(zn + (size_t)ti * 32768);
    const i64x2* Bp = reinterpret_cast<const i64x2*>(zn + (size_t)tj * 32768);

    f32x4 acc[4][4];
#pragma unroll
    for (int r = 0; r < 4; ++r)
#pragma unroll
        for (int c = 0; c < 4; ++c) acc[r][c] = (f32x4){0.f, 0.f, 0.f, 0.f};

#pragma unroll
    for (int kkp = 0; kkp < 4; ++kkp) {
        i64x2 a_[4], b_[4];
#pragma unroll
        for (int r = 0; r < 4; ++r)
            a_[r] = Ap[((wr * 4 + r) * 4 + kkp) * 64 + lane];
#pragma unroll
        for (int c = 0; c < 4; ++c)
            b_[c] = Bp[((wc * 4 + c) * 4 + kkp) * 64 + lane];
#pragma unroll
        for (int r = 0; r < 4; ++r)
#pragma unroll
            for (int c = 0; c < 4; ++c) {
                acc[r][c] = __builtin_amdgcn_mfma_f32_16x16x32_fp8_fp8(
                    a_[r].x, b_[c].x, acc[r][c], 0, 0, 0);
                acc[r][c] = __builtin_amdgcn_mfma_f32_16x16x32_fp8_fp8(
                    a_[r].y, b_[c].y, acc[r][c], 0, 0, 0);
            }
    }

    // tail: e = exp(2*sim); row-sums -> plane 2*tj+wc; col-sums -> plane
    // 2*ti+wr (off-diag only). row = wr*64+r*16+lhi*4+q, col = wc*64+c*16+l15.
    float cs[4] = {0.f, 0.f, 0.f, 0.f};
#pragma unroll
    for (int r = 0; r < 4; ++r) {
        float rq0 = 0.f, rq1 = 0.f, rq2 = 0.f, rq3 = 0.f;
#pragma unroll
        for (int c = 0; c < 4; ++c) {
            float e0 = fexp2(KEXP2 * acc[r][c][0]);
            float e1 = fexp2(KEXP2 * acc[r][c][1]);
            float e2 = fexp2(KEXP2 * acc[r][c][2]);
            float e3 = fexp2(KEXP2 * acc[r][c][3]);
            rq0 += e0; rq1 += e1; rq2 += e2; rq3 += e3;
            cs[c] += e0 + e1 + e2 + e3;
        }
#pragma unroll
        for (int off = 1; off <= 8; off <<= 1) {
            rq0 += __shfl_xor(rq0, off, 64);
            rq1 += __shfl_xor(rq1, off, 64);
            rq2 += __shfl_xor(rq2, off, 64);
            rq3 += __shfl_xor(rq3, off, 64);
        }
        if (l15 == 0) {
            f32x4 o = (f32x4){rq0, rq1, rq2, rq3};
            *reinterpret_cast<f32x4*>(
                P + (size_t)(2 * tj + wc) * N + ti * 128 + wr * 64 + r * 16 + lhi * 4) = o;
        }
    }
    if (ti != tj) {
#pragma unroll
        for (int c = 0; c < 4; ++c) {
            float v = cs[c];
            v += __shfl_xor(v, 16, 64);
            v += __shfl_xor(v, 32, 64);
            if (lhi == 0)
                P[(size_t)(2 * ti + wr) * N + tj * 128 + wc * 64 + c * 16 + l15] = v;
        }
    }
}

// Kernel 3: COALESCED per-row plane sum (1 thread/row: a wave reads 64
// consecutive rows of one plane per load -- R15's 8-thread/row split made
// lanes hit 8 planes 512KB apart = 16x over-fetch) + diag, log; block
// partial; last block (verified counter pattern) combines with pos partials.
__global__ void k_lse(const float* __restrict__ P, const float* __restrict__ diag,
                      const float* __restrict__ pos_partial, int n_pos,
                      float* __restrict__ part, unsigned int* __restrict__ counter,
                      float* __restrict__ out, int N) {
    __shared__ float red[4];
    const int tid = threadIdx.x;
    const int lane = tid & 63, wv = tid >> 6;
    const int row = blockIdx.x * 256 + tid;
    float s = diag[row];
#pragma unroll 16
    for (int k = 0; k < NPLANE; ++k) s += P[(size_t)k * N + row];
    float local = __logf(s);
#pragma unroll
    for (int off = 32; off >= 1; off >>= 1) local += __shfl_xor(local, off, 64);
    if (lane == 0) red[wv] = local;
    __syncthreads();
    bool last = false;
    if (tid == 0) {
        part[blockIdx.x] = red[0] + red[1] + red[2] + red[3];
        __threadfence();
        last = (atomicAdd(counter, 1u) == LSE_BLOCKS - 1);
    }
    __shared__ int lastflag;
    if (tid == 0) lastflag = last ? 1 : 0;
    __syncthreads();
    if (lastflag) {
        __threadfence();
        float t = 0.f;
        for (int i = tid; i < LSE_BLOCKS; i += 256) t += part[i];
        for (int i = tid; i < n_pos; i += 256) t -= pos_partial[i];
#pragma unroll
        for (int off = 32; off >= 1; off >>= 1) t += __shfl_xor(t, off, 64);
        if (lane == 0) red[wv] = t;
        __syncthreads();
        if (tid == 0)
            out[0] = (red[0] + red[1] + red[2] + red[3]) / (float)N;
    }
}

extern "C" void kernel_launch(void* const* d_in, const int* in_sizes, int n_in,
                              void* d_out, int out_size, void* d_ws, size_t ws_size,
                              hipStream_t stream) {
    const float* zi = (const float*)d_in[0];
    const float* zj = (const float*)d_in[1];
    const int B = in_sizes[0] / D;   // 4096
    const int N = 2 * B;             // 8192

    char* ws = (char*)d_ws;
    unsigned char* zn = (unsigned char*)ws;              // N*D fp8 = 2 MB
    float* diag = (float*)(ws + (size_t)N * D);          // N f32
    float* pos_partial = diag + N;                       // 1024 f32
    float* part = pos_partial + 1024;                    // 32 f32
    unsigned int* counter = (unsigned int*)(part + 32);  // 1 u32
    float* P = (float*)(counter + 32);                   // 128*N f32 = 4 MB

    float* out = (float*)d_out;

    const int npb = B / 4;  // 1024 k_norm blocks == pos partials
    hipLaunchKernelGGL(k_norm, dim3(npb), dim3(256), 0, stream, zi, zj, zn, diag,
                       pos_partial, counter, B);
    hipLaunchKernelGGL(k_main, dim3(NT), dim3(256), 0, stream, zn, P, N);
    hipLaunchKernelGGL(k_lse, dim3(LSE_BLOCKS), dim3(256), 0, stream, P, diag,
                       pos_partial, npb, part, counter, out, N);
}